// Round 10
// baseline (204.659 us; speedup 1.0000x reference)
//
#include <hip/hip_runtime.h>

#define NR 131072
#define DD 32
#define KK 64
#define BETA_C 10.0f
#define WROWS 256                    // rows per syrk worker
#define GRIDW 640                    // >= sum ceil(c_k/WROWS) <= 512+64 = 576
#define TRI(i, j) ((i) * ((i) + 1) / 2 + (j))

// ---------------------------------------------------------------------------
// R17 = R15 base (validated best, 129.4) + phase1 v4 (only change).
// Root cause nailed by R11/R12/R16 VGPR counters (56/56/40 vs live sets
// 112/112/70): the allocator targets ~64 regs regardless of launch_bounds
// and ALWAYS dumps the pv[] softmax array to scratch; the per-thread
// scratch round-trip is phase1's 40-50 us. v4 removes the array
// structurally: 3-pass recompute, live set ~50 regs.
//   pass A : 4-way ILP dots -> best/bi only (argmin bit-identical).
//   pass B1: recompute dots -> ssum += e_k, single sequential ascending-k
//            chain (bit-identical to validated).
//   pass B2: 4 chunks x 16: recompute dots -> e*inv in a 16-reg array
//            (static-indexed, promotes) -> 4-bit transpose butterfly
//            (m=8,4,2,1 over lane bits 3..0) + shfl16/shfl32 group sum.
//            Only the fill summation TREE changes -> absmax ~1e-8;
//            pred/hist/ssum/means/covs exact.
// Extra cost: 3x dot FMAs ~= 10 us chip-wide, far below the ~40 us of
// scratch traffic removed.
//
// ws layout (float-indexed):
//   [0,64)   fill_g   [64,65) lossAcc   [67,68) doneF(int)
//   [128,192) hist_g (int)   [320,384) cursor (int)
//   [1824,35616) m2low_g (K x 528 tri)  [35616,37664) sums_g (K x 32)
//   [37664,70432) pred8 (uchar N)       [70432,+N) idx (uint N, 512 KB)
// memset zeroes [0,384) floats only; m2low/sums zeroed by scatter.
// ---------------------------------------------------------------------------

#define DOT4(kb, dA, dB, dC, dD2)                                   \
  {                                                                 \
    const float* c0 = centers + (4 * (kb) + 0) * DD;                \
    const float* c1 = centers + (4 * (kb) + 1) * DD;                \
    const float* c2 = centers + (4 * (kb) + 2) * DD;                \
    const float* c3 = centers + (4 * (kb) + 3) * DD;                \
    _Pragma("unroll") for (int j = 0; j < DD; ++j) {                \
      const float xj = xr[j];                                       \
      dA += xj * c0[j];                                             \
      dB += xj * c1[j];                                             \
      dC += xj * c2[j];                                             \
      dD2 += xj * c3[j];                                            \
    }                                                               \
  }

// phase 1 v4: one row/thread, 512 blocks x 256 thr; centers on the
// wave-uniform s_load path; NO pv[64] array (3-pass recompute).
__global__ __launch_bounds__(256) void phase1_kernel(
    const float* __restrict__ x, const float* __restrict__ centers,
    float* __restrict__ fill_g, int* __restrict__ hist_g,
    unsigned char* __restrict__ pred_g) {
  __shared__ float cnS[KK];
  __shared__ float fillW[4][KK];
  __shared__ int histS[KK];

  const int tid = threadIdx.x;
  const int lane = tid & 63;
  const int wid = tid >> 6;

  if (tid < KK) {
    float s = 0.f;
    const float* cp = centers + tid * DD;
#pragma unroll
    for (int j = 0; j < DD; ++j) s += cp[j] * cp[j];
    cnS[tid] = s;
    histS[tid] = 0;
  }
  __syncthreads();

  const int row = blockIdx.x * 256 + tid;  // grid == NR/256 exactly

  float xr[DD];
  const float4* xp = (const float4*)(x + (size_t)row * DD);
#pragma unroll
  for (int j = 0; j < 8; ++j) {
    const float4 v = xp[j];
    xr[4 * j + 0] = v.x;
    xr[4 * j + 1] = v.y;
    xr[4 * j + 2] = v.z;
    xr[4 * j + 3] = v.w;
  }
  float xx = 0.f;
#pragma unroll
  for (int j = 0; j < DD; ++j) xx += xr[j] * xr[j];

  // ---- pass A: argmin (no storage). d2 chain identical to validated. ----
  float best = 3.4e38f;
  int bi = 0;
#pragma unroll
  for (int kb = 0; kb < KK / 4; ++kb) {
    float dA = 0.f, dB = 0.f, dC = 0.f, dD2 = 0.f;
    DOT4(kb, dA, dB, dC, dD2);
    const float e0 = xx - 2.0f * dA + cnS[4 * kb + 0];
    const float e1 = xx - 2.0f * dB + cnS[4 * kb + 1];
    const float e2 = xx - 2.0f * dC + cnS[4 * kb + 2];
    const float e3 = xx - 2.0f * dD2 + cnS[4 * kb + 3];
    if (e0 < best) { best = e0; bi = 4 * kb + 0; }  // ascending k:
    if (e1 < best) { best = e1; bi = 4 * kb + 1; }  // strict < == first-
    if (e2 < best) { best = e2; bi = 4 * kb + 2; }  // index ties, as
    if (e3 < best) { best = e3; bi = 4 * kb + 3; }  // validated
  }
  pred_g[row] = (unsigned char)bi;
  atomicAdd(&histS[bi], 1);

  // ---- pass B1: ssum, single sequential ascending-k chain (exact). ----
  float ssum = 0.f;
#pragma unroll
  for (int kb = 0; kb < KK / 4; ++kb) {
    float dA = 0.f, dB = 0.f, dC = 0.f, dD2 = 0.f;
    DOT4(kb, dA, dB, dC, dD2);
    ssum += __expf(BETA_C * (best - (xx - 2.0f * dA + cnS[4 * kb + 0])));
    ssum += __expf(BETA_C * (best - (xx - 2.0f * dB + cnS[4 * kb + 1])));
    ssum += __expf(BETA_C * (best - (xx - 2.0f * dC + cnS[4 * kb + 2])));
    ssum += __expf(BETA_C * (best - (xx - 2.0f * dD2 + cnS[4 * kb + 3])));
  }
  const float inv = 1.0f / ssum;

  // ---- pass B2: fill, 4 chunks of 16 k's; 16-reg array per chunk. ----
#pragma unroll
  for (int c = 0; c < 4; ++c) {
    float ev[16];
#pragma unroll
    for (int q = 0; q < 4; ++q) {
      const int kb = 4 * c + q;
      float dA = 0.f, dB = 0.f, dC = 0.f, dD2 = 0.f;
      DOT4(kb, dA, dB, dC, dD2);
      ev[4 * q + 0] =
          __expf(BETA_C * (best - (xx - 2.0f * dA + cnS[4 * kb + 0]))) * inv;
      ev[4 * q + 1] =
          __expf(BETA_C * (best - (xx - 2.0f * dB + cnS[4 * kb + 1]))) * inv;
      ev[4 * q + 2] =
          __expf(BETA_C * (best - (xx - 2.0f * dC + cnS[4 * kb + 2]))) * inv;
      ev[4 * q + 3] =
          __expf(BETA_C * (best - (xx - 2.0f * dD2 + cnS[4 * kb + 3]))) * inv;
    }
    // 16-value transpose-reduce over lane bits 3..0: lane 16g+s ends with
    // group-g's row-sum for k = 16c+s.
#pragma unroll
    for (int m = 8; m >= 1; m >>= 1) {
      const bool hi = (lane & m) != 0;
#pragma unroll
      for (int i = 0; i < m; ++i) {
        const float send = hi ? ev[i] : ev[i + m];
        const float recv = __shfl_xor(send, m, 64);
        const float keep = hi ? ev[i + m] : ev[i];
        ev[i] = keep + recv;
      }
    }
    float f = ev[0];
    f += __shfl_xor(f, 16, 64);  // sum the 4 sixteen-lane groups
    f += __shfl_xor(f, 32, 64);
    if (lane < 16) fillW[wid][16 * c + lane] = f;
  }
  __syncthreads();
  if (tid < KK) {
    atomicAdd(&fill_g[tid],
              fillW[0][tid] + fillW[1][tid] + fillW[2][tid] + fillW[3][tid]);
    if (histS[tid]) atomicAdd(&hist_g[tid], histS[tid]);
  }
}

// scatter v3 (R15 verbatim, validated): counting-sort of ROW INDICES;
// self-plans segment bases via in-block scan of hist_g; zeroes m2low/sums.
__global__ __launch_bounds__(256) void scatter_kernel(
    const unsigned char* __restrict__ pred_g, const int* __restrict__ hist_g,
    int* __restrict__ cursor, unsigned int* __restrict__ idxg,
    float4* __restrict__ m2zero) {
  __shared__ int histS[KK];
  __shared__ int baseS[KK];

  const int tid = threadIdx.x;
  if (tid < 18) {  // zero m2low_g + sums_g: 35840 floats = 8960 float4
    const int z = blockIdx.x * 18 + tid;
    if (z < 8960) m2zero[z] = make_float4(0.f, 0.f, 0.f, 0.f);
  }
  if (tid < KK) histS[tid] = 0;
  __syncthreads();

  const int row = blockIdx.x * 256 + tid;
  const int bi = pred_g[row];
  const int rank = atomicAdd(&histS[bi], 1);
  __syncthreads();
  if (tid < KK) {  // threads 0..63 == wave 0: shuffle-scan is safe
    const int c = hist_g[tid];
    int inc = c;
#pragma unroll
    for (int off = 1; off < 64; off <<= 1) {
      const int v = __shfl_up(inc, off, 64);
      if (tid >= off) inc += v;
    }
    const int seg = inc - c;  // exclusive scan == segStart[tid]
    const int h = histS[tid];
    baseS[tid] = seg + (h ? atomicAdd(&cursor[tid], h) : 0);
  }
  __syncthreads();
  idxg[baseS[bi] + rank] = (unsigned int)row;  // ~4-row runs per cluster
}

// syrk v5 (R15 verbatim, validated): self-planning worker; gather via index
// list into transposed LDS tile; 4 wave-groups x 4x4 register tiles; LDS
// reduction; triangular flush.
__global__ __launch_bounds__(256) void syrk_kernel(
    const float* __restrict__ x, const unsigned int* __restrict__ idxg,
    const int* __restrict__ hist_g, float* __restrict__ m2low_g,
    float* __restrict__ sums_g) {
  __shared__ float xsT[DD][68];    // transposed tile, 8.7 KB (rows of 17 f4)
  __shared__ float red[4][64][16]; // per-group 4x4-tile partials, 16 KB
  __shared__ float sdred[4][DD];   // per-group row sums, 0.5 KB
  __shared__ int planS[3];         // k, base, cnt

  const int tid = threadIdx.x;
  if (tid < 64) {  // wave 0: derive this block's worker assignment
    const int c = hist_g[tid];
    int inc = c;
#pragma unroll
    for (int off = 1; off < 64; off <<= 1) {
      const int v = __shfl_up(inc, off, 64);
      if (tid >= off) inc += v;
    }
    const int seg = inc - c;
    const int nw = (c + WROWS - 1) / WROWS;
    int winc = nw;
#pragma unroll
    for (int off = 1; off < 64; off <<= 1) {
      const int v = __shfl_up(winc, off, 64);
      if (tid >= off) winc += v;
    }
    const int woff = winc - nw;
    const int wtot = __shfl(winc, 63, 64);  // total workers <= 576
    const int b = blockIdx.x;
    if (b >= wtot) {
      if (tid == 0) planS[0] = 255;
    } else if (b >= woff && b < woff + nw) {  // exactly one lane
      const int wi = b - woff;
      planS[0] = tid;
      planS[1] = seg + wi * WROWS;
      planS[2] = min(WROWS, c - wi * WROWS);
    }
  }
  __syncthreads();
  const int k = planS[0];
  if (k == 255) return;  // uniform exit after barrier
  const int base = planS[1];
  const int total = planS[2];

  const int grp = tid >> 6;   // 4 groups == 4 waves
  const int t6 = tid & 63;
  const int ti = t6 >> 3;     // 0..7: output rows i = ti + 8r, r=0..3
  const int tj = t6 & 7;      // 0..7: output cols j = tj + 8c, c=0..3

  float cc[4][4];
#pragma unroll
  for (int r = 0; r < 4; ++r)
#pragma unroll
    for (int c2 = 0; c2 < 4; ++c2) cc[r][c2] = 0.f;
  float sd[4] = {0.f, 0.f, 0.f, 0.f};

  const float4* xf4 = (const float4*)x;
  const int rl0 = tid >> 3;       // row-local for pass 0 (0..31)
  const int pt = tid & 7;         // float4 slot within row

  for (int off = 0; off < total; off += 64) {
    const int cnt = min(64, total - off);
    const int cnt4 = (cnt + 3) & ~3;
    __syncthreads();  // previous tile's readers done before overwrite

    if (rl0 < cnt) {
      const unsigned int r0 = idxg[base + off + rl0];
      const float4 v = xf4[(size_t)r0 * 8 + pt];
      xsT[pt * 4 + 0][rl0] = v.x;
      xsT[pt * 4 + 1][rl0] = v.y;
      xsT[pt * 4 + 2][rl0] = v.z;
      xsT[pt * 4 + 3][rl0] = v.w;
    }
    const int rl1 = rl0 + 32;
    if (rl1 < cnt) {
      const unsigned int r1 = idxg[base + off + rl1];
      const float4 v = xf4[(size_t)r1 * 8 + pt];
      xsT[pt * 4 + 0][rl1] = v.x;
      xsT[pt * 4 + 1][rl1] = v.y;
      xsT[pt * 4 + 2][rl1] = v.z;
      xsT[pt * 4 + 3][rl1] = v.w;
    }
    for (int e = cnt * DD + tid; e < cnt4 * DD; e += 256)
      xsT[e & 31][e >> 5] = 0.f;  // zero-pad rows to multiple of 4
    __syncthreads();

    const int gmax = cnt4 >> 2;
    for (int g = grp; g < gmax; g += 4) {  // row-quads strided by group
      float4 Af[4], Bf[4];
#pragma unroll
      for (int r = 0; r < 4; ++r)
        Af[r] = *(const float4*)&xsT[ti + 8 * r][4 * g];
#pragma unroll
      for (int c2 = 0; c2 < 4; ++c2)
        Bf[c2] = *(const float4*)&xsT[tj + 8 * c2][4 * g];
#pragma unroll
      for (int r = 0; r < 4; ++r)
#pragma unroll
        for (int c2 = 0; c2 < 4; ++c2)
          cc[r][c2] += Af[r].x * Bf[c2].x + Af[r].y * Bf[c2].y +
                       Af[r].z * Bf[c2].z + Af[r].w * Bf[c2].w;
      if (tj == 0) {
#pragma unroll
        for (int r = 0; r < 4; ++r)
          sd[r] += Af[r].x + Af[r].y + Af[r].z + Af[r].w;
      }
    }
  }

  // cross-group reduction through LDS, then triangular flush
#pragma unroll
  for (int r = 0; r < 4; ++r)
    *(float4*)&red[grp][t6][r * 4] =
        make_float4(cc[r][0], cc[r][1], cc[r][2], cc[r][3]);
  if (tj == 0) {
#pragma unroll
    for (int r = 0; r < 4; ++r) sdred[grp][ti + 8 * r] = sd[r];
  }
  __syncthreads();

  float* m2k = m2low_g + k * 528;
  {
    const int t6r = tid >> 2;        // which 4x4 tile (0..63)
    const int rr = tid & 3;          // which row of that tile
    const int tir = t6r >> 3, tjr = t6r & 7;
    const int i = tir + 8 * rr;
    float4 v0 = *(const float4*)&red[0][t6r][rr * 4];
    const float4 v1 = *(const float4*)&red[1][t6r][rr * 4];
    const float4 v2 = *(const float4*)&red[2][t6r][rr * 4];
    const float4 v3 = *(const float4*)&red[3][t6r][rr * 4];
    v0.x += v1.x + v2.x + v3.x;
    v0.y += v1.y + v2.y + v3.y;
    v0.z += v1.z + v2.z + v3.z;
    v0.w += v1.w + v2.w + v3.w;
    const float vv[4] = {v0.x, v0.y, v0.z, v0.w};
#pragma unroll
    for (int q = 0; q < 4; ++q) {
      const int j = tjr + 8 * q;
      if (j <= i) atomicAdd(&m2k[TRI(i, j)], vv[q]);
    }
  }
  if (tid < DD) {
    const float s =
        sdred[0][tid] + sdred[1][tid] + sdred[2][tid] + sdred[3][tid];
    atomicAdd(&sums_g[k * DD + tid], s);
  }
}

// finalize (R15 verbatim, validated): one block per cluster; last-arriving
// block writes the output scalar (fence only at pipeline END).
__global__ __launch_bounds__(256) void finalize_kernel(
    const float* __restrict__ fill_g, const int* __restrict__ hist_g,
    const float* __restrict__ sums_g, const float* __restrict__ m2low_g,
    const float* __restrict__ ft, const float* __restrict__ mt,
    const float* __restrict__ ct, float* __restrict__ lossAcc,
    int* __restrict__ doneF, float* __restrict__ out) {
  __shared__ float meanS[DD];
  __shared__ float wred[4];
  const int t = threadIdx.x;
  const int k = blockIdx.x;

  const float inv = 1.0f / fmaxf((float)hist_g[k], 1.0f);
  if (t < DD) meanS[t] = sums_g[k * DD + t] * inv;
  __syncthreads();

  float acc = 0.f;
  if (t < DD) {
    const float d = meanS[t] - mt[k * DD + t];
    acc += d * d * (1.0f / (KK * DD));
  }
  if (t == 0) {
    const float f = fill_g[k] * (1.0f / (float)NR) - ft[k];
    acc += f * f * (1.0f / KK);
  }
  const float* m2k = m2low_g + k * 528;
  const float* ctk = ct + k * (DD * DD);
#pragma unroll
  for (int u = 0; u < 4; ++u) {
    const int e = t + 256 * u;
    const int i = e >> 5, j = e & 31;
    const int idx = (i >= j) ? TRI(i, j) : TRI(j, i);
    const float cov = m2k[idx] * inv - meanS[i] * meanS[j];
    const float d = cov - ctk[e];
    acc += d * d * (1.0f / (KK * DD * DD));
  }

  acc += __shfl_xor(acc, 32, 64);
  acc += __shfl_xor(acc, 16, 64);
  acc += __shfl_xor(acc, 8, 64);
  acc += __shfl_xor(acc, 4, 64);
  acc += __shfl_xor(acc, 2, 64);
  acc += __shfl_xor(acc, 1, 64);
  if ((t & 63) == 0) wred[t >> 6] = acc;
  __syncthreads();
  if (t == 0) {
    atomicAdd(lossAcc, wred[0] + wred[1] + wred[2] + wred[3]);
    __threadfence();  // release: lossAcc visible before doneF bump
    if (atomicAdd(doneF, 1) == KK - 1) {
      out[0] = atomicAdd(lossAcc, 0.0f);  // coherent-path read
    }
  }
}

extern "C" void kernel_launch(void* const* d_in, const int* in_sizes, int n_in,
                              void* d_out, int out_size, void* d_ws,
                              size_t ws_size, hipStream_t stream) {
  (void)in_sizes; (void)n_in; (void)out_size; (void)ws_size;
  const float* x = (const float*)d_in[0];
  const float* centers = (const float*)d_in[1];
  const float* ft = (const float*)d_in[2];
  const float* mt = (const float*)d_in[3];
  const float* ct = (const float*)d_in[4];
  float* out = (float*)d_out;

  float* ws = (float*)d_ws;
  float* fill_g = ws;                                   // 64
  float* lossAcc = ws + 64;                             // 1
  int* doneF = (int*)(ws + 67);                         // 1
  int* hist_g = (int*)(ws + 128);                       // 64
  int* cursor = (int*)(ws + 320);                       // 64
  float* m2low_g = ws + 1824;                           // 33792
  float* sums_g = ws + 35616;                           // 2048
  unsigned char* pred8 = (unsigned char*)(ws + 37664);  // N bytes
  unsigned int* idxg = (unsigned int*)(ws + 70432);     // N uints (512 KB)

  // zero fill_g/lossAcc/doneF/hist/cursor only (1.5 KB); m2low/sums are
  // zeroed inside scatter (stream-ordered ahead of syrk's atomics).
  hipMemsetAsync(d_ws, 0, (size_t)384 * sizeof(float), stream);

  phase1_kernel<<<NR / 256, 256, 0, stream>>>(x, centers, fill_g, hist_g,
                                              pred8);
  scatter_kernel<<<NR / 256, 256, 0, stream>>>(pred8, hist_g, cursor, idxg,
                                               (float4*)m2low_g);
  syrk_kernel<<<GRIDW, 256, 0, stream>>>(x, idxg, hist_g, m2low_g, sums_g);
  finalize_kernel<<<KK, 256, 0, stream>>>(fill_g, hist_g, sums_g, m2low_g, ft,
                                          mt, ct, lossAcc, doneF, out);
}

// Round 12
// 146.253 us; speedup vs baseline: 1.3994x; 1.3994x over previous
//
#include <hip/hip_runtime.h>

#define NR 131072
#define DD 32
#define KK 64
#define BETA_C 10.0f
#define WROWS 256                    // rows per syrk worker
#define GRIDW 640                    // >= sum ceil(c_k/WROWS) <= 512+64 = 576
#define TRI(i, j) ((i) * ((i) + 1) / 2 + (j))

// ---------------------------------------------------------------------------
// R19 == R18 resubmit (container infra died twice, zero signal on the kernel).
// R18 = R15 pipeline (validated 129.4) + phase1 v5 (only change).
// Evidence chain: R17 proved each dot-pass through the scalar centers[] feed
// costs ~35 us (3 passes = 107 us, VGPR=120 -> no spill issue); R12/R11's
// ~35-40 us phase1 = ONE such pass. The feed is the bottleneck, not FMA
// (floor 3.4 us) and not spills. R13's LDS regression is explained by its 4x
// x-read duplication (+10 us HBM), not by LDS itself. v5: R12 structure
// (1 row/thread, pv[64], (256,2) -> 128-VGPR budget for ~110 live regs),
// centers staged once into LDS and read as float4 with ALL 64 lanes at the
// SAME address (pure broadcast, conflict-free); dot loop = R14's 4-way
// k-interleave (exactness validated), j ascending within each chain ->
// d2/argmin/ssum/fill chains bit-identical to the validated kernel.
// Per wave: 512 ds_read_b128 (~6k cyc) vs 2048 fmac (~4k cyc) -> ~5 us/SIMD.
//
// ws layout (float-indexed):
//   [0,64)   fill_g   [64,65) lossAcc   [67,68) doneF(int)
//   [128,192) hist_g (int)   [320,384) cursor (int)
//   [1824,35616) m2low_g (K x 528 tri)  [35616,37664) sums_g (K x 32)
//   [37664,70432) pred8 (uchar N)       [70432,+N) idx (uint N, 512 KB)
// memset zeroes [0,384) floats only; m2low/sums zeroed by scatter.
// ---------------------------------------------------------------------------

// phase 1 v5: one row/thread, 512 blocks x 256 thr; centers in LDS, float4
// broadcast reads; 4-way k-interleaved dot chains; R12 epilogue verbatim.
__global__ __launch_bounds__(256, 2) void phase1_kernel(
    const float* __restrict__ x, const float* __restrict__ centers,
    float* __restrict__ fill_g, int* __restrict__ hist_g,
    unsigned char* __restrict__ pred_g) {
  __shared__ float4 cS4[KK * 8];   // centers, 8 KB; index k*8+jc
  __shared__ float cnS[KK];
  __shared__ float fillW[4][KK];
  __shared__ int histS[KK];

  const int tid = threadIdx.x;
  const int lane = tid & 63;
  const int wid = tid >> 6;

  // stage centers (512 float4 by 256 threads, coalesced)
  {
    const float4* cg = (const float4*)centers;
    cS4[tid] = cg[tid];
    cS4[tid + 256] = cg[tid + 256];
    if (tid < KK) histS[tid] = 0;
  }
  __syncthreads();
  if (tid < KK) {
    float s = 0.f;
#pragma unroll
    for (int jc = 0; jc < 8; ++jc) {  // ascending j, same chain as validated
      const float4 c = cS4[tid * 8 + jc];
      s += c.x * c.x;
      s += c.y * c.y;
      s += c.z * c.z;
      s += c.w * c.w;
    }
    cnS[tid] = s;
  }
  __syncthreads();

  const int row = blockIdx.x * 256 + tid;  // grid == NR/256 exactly

  float xr[DD];
  const float4* xp = (const float4*)(x + (size_t)row * DD);
#pragma unroll
  for (int j = 0; j < 8; ++j) {
    const float4 v = xp[j];
    xr[4 * j + 0] = v.x;
    xr[4 * j + 1] = v.y;
    xr[4 * j + 2] = v.z;
    xr[4 * j + 3] = v.w;
  }
  float xx = 0.f;
#pragma unroll
  for (int j = 0; j < DD; ++j) xx += xr[j] * xr[j];

  float pv[KK];
  float best = 3.4e38f;
  int bi = 0;
  // 4-way k-interleave (R14-validated exactness); centers via LDS broadcast:
  // every lane reads the SAME cS4 element -> conflict-free ds_read_b128.
#pragma unroll
  for (int kb = 0; kb < KK / 4; ++kb) {
    float dA = 0.f, dB = 0.f, dC = 0.f, dD2 = 0.f;
#pragma unroll
    for (int jc = 0; jc < 8; ++jc) {
      const float4 a = cS4[(4 * kb + 0) * 8 + jc];
      const float4 b = cS4[(4 * kb + 1) * 8 + jc];
      const float4 c = cS4[(4 * kb + 2) * 8 + jc];
      const float4 d = cS4[(4 * kb + 3) * 8 + jc];
      const float x0 = xr[4 * jc + 0];
      const float x1 = xr[4 * jc + 1];
      const float x2 = xr[4 * jc + 2];
      const float x3 = xr[4 * jc + 3];
      dA += x0 * a.x; dA += x1 * a.y; dA += x2 * a.z; dA += x3 * a.w;
      dB += x0 * b.x; dB += x1 * b.y; dB += x2 * b.z; dB += x3 * b.w;
      dC += x0 * c.x; dC += x1 * c.y; dC += x2 * c.z; dC += x3 * c.w;
      dD2 += x0 * d.x; dD2 += x1 * d.y; dD2 += x2 * d.z; dD2 += x3 * d.w;
    }
    const float e0 = xx - 2.0f * dA + cnS[4 * kb + 0];
    const float e1 = xx - 2.0f * dB + cnS[4 * kb + 1];
    const float e2 = xx - 2.0f * dC + cnS[4 * kb + 2];
    const float e3 = xx - 2.0f * dD2 + cnS[4 * kb + 3];
    pv[4 * kb + 0] = e0;
    pv[4 * kb + 1] = e1;
    pv[4 * kb + 2] = e2;
    pv[4 * kb + 3] = e3;
    if (e0 < best) { best = e0; bi = 4 * kb + 0; }  // ascending k: strict <
    if (e1 < best) { best = e1; bi = 4 * kb + 1; }  // == first-index ties
    if (e2 < best) { best = e2; bi = 4 * kb + 2; }
    if (e3 < best) { best = e3; bi = 4 * kb + 3; }
  }
  pred_g[row] = (unsigned char)bi;
  atomicAdd(&histS[bi], 1);

  float ssum = 0.f;
#pragma unroll
  for (int k = 0; k < KK; ++k) {
    const float e = __expf(BETA_C * (best - pv[k]));
    pv[k] = e;
    ssum += e;
  }
  const float inv = 1.0f / ssum;
#pragma unroll
  for (int k = 0; k < KK; ++k) pv[k] *= inv;

#pragma unroll
  for (int m = 32; m >= 1; m >>= 1) {
    const bool hi = (lane & m) != 0;
#pragma unroll
    for (int i = 0; i < m; ++i) {
      const float send = hi ? pv[i] : pv[i + m];
      const float recv = __shfl_xor(send, m, 64);
      const float keep = hi ? pv[i + m] : pv[i];
      pv[i] = keep + recv;
    }
  }
  fillW[wid][lane] = pv[0];
  __syncthreads();
  if (tid < KK) {
    atomicAdd(&fill_g[tid],
              fillW[0][tid] + fillW[1][tid] + fillW[2][tid] + fillW[3][tid]);
    if (histS[tid]) atomicAdd(&hist_g[tid], histS[tid]);
  }
}

// scatter v3 (R15 verbatim, validated): counting-sort of ROW INDICES;
// self-plans segment bases via in-block scan of hist_g; zeroes m2low/sums.
__global__ __launch_bounds__(256) void scatter_kernel(
    const unsigned char* __restrict__ pred_g, const int* __restrict__ hist_g,
    int* __restrict__ cursor, unsigned int* __restrict__ idxg,
    float4* __restrict__ m2zero) {
  __shared__ int histS[KK];
  __shared__ int baseS[KK];

  const int tid = threadIdx.x;
  if (tid < 18) {  // zero m2low_g + sums_g: 35840 floats = 8960 float4
    const int z = blockIdx.x * 18 + tid;
    if (z < 8960) m2zero[z] = make_float4(0.f, 0.f, 0.f, 0.f);
  }
  if (tid < KK) histS[tid] = 0;
  __syncthreads();

  const int row = blockIdx.x * 256 + tid;
  const int bi = pred_g[row];
  const int rank = atomicAdd(&histS[bi], 1);
  __syncthreads();
  if (tid < KK) {  // threads 0..63 == wave 0: shuffle-scan is safe
    const int c = hist_g[tid];
    int inc = c;
#pragma unroll
    for (int off = 1; off < 64; off <<= 1) {
      const int v = __shfl_up(inc, off, 64);
      if (tid >= off) inc += v;
    }
    const int seg = inc - c;  // exclusive scan == segStart[tid]
    const int h = histS[tid];
    baseS[tid] = seg + (h ? atomicAdd(&cursor[tid], h) : 0);
  }
  __syncthreads();
  idxg[baseS[bi] + rank] = (unsigned int)row;  // ~4-row runs per cluster
}

// syrk v5 (R15 verbatim, validated): self-planning worker; gather via index
// list into transposed LDS tile; 4 wave-groups x 4x4 register tiles; LDS
// reduction; triangular flush.
__global__ __launch_bounds__(256) void syrk_kernel(
    const float* __restrict__ x, const unsigned int* __restrict__ idxg,
    const int* __restrict__ hist_g, float* __restrict__ m2low_g,
    float* __restrict__ sums_g) {
  __shared__ float xsT[DD][68];    // transposed tile, 8.7 KB (rows of 17 f4)
  __shared__ float red[4][64][16]; // per-group 4x4-tile partials, 16 KB
  __shared__ float sdred[4][DD];   // per-group row sums, 0.5 KB
  __shared__ int planS[3];         // k, base, cnt

  const int tid = threadIdx.x;
  if (tid < 64) {  // wave 0: derive this block's worker assignment
    const int c = hist_g[tid];
    int inc = c;
#pragma unroll
    for (int off = 1; off < 64; off <<= 1) {
      const int v = __shfl_up(inc, off, 64);
      if (tid >= off) inc += v;
    }
    const int seg = inc - c;
    const int nw = (c + WROWS - 1) / WROWS;
    int winc = nw;
#pragma unroll
    for (int off = 1; off < 64; off <<= 1) {
      const int v = __shfl_up(winc, off, 64);
      if (tid >= off) winc += v;
    }
    const int woff = winc - nw;
    const int wtot = __shfl(winc, 63, 64);  // total workers <= 576
    const int b = blockIdx.x;
    if (b >= wtot) {
      if (tid == 0) planS[0] = 255;
    } else if (b >= woff && b < woff + nw) {  // exactly one lane
      const int wi = b - woff;
      planS[0] = tid;
      planS[1] = seg + wi * WROWS;
      planS[2] = min(WROWS, c - wi * WROWS);
    }
  }
  __syncthreads();
  const int k = planS[0];
  if (k == 255) return;  // uniform exit after barrier
  const int base = planS[1];
  const int total = planS[2];

  const int grp = tid >> 6;   // 4 groups == 4 waves
  const int t6 = tid & 63;
  const int ti = t6 >> 3;     // 0..7: output rows i = ti + 8r, r=0..3
  const int tj = t6 & 7;      // 0..7: output cols j = tj + 8c, c=0..3

  float cc[4][4];
#pragma unroll
  for (int r = 0; r < 4; ++r)
#pragma unroll
    for (int c2 = 0; c2 < 4; ++c2) cc[r][c2] = 0.f;
  float sd[4] = {0.f, 0.f, 0.f, 0.f};

  const float4* xf4 = (const float4*)x;
  const int rl0 = tid >> 3;       // row-local for pass 0 (0..31)
  const int pt = tid & 7;         // float4 slot within row

  for (int off = 0; off < total; off += 64) {
    const int cnt = min(64, total - off);
    const int cnt4 = (cnt + 3) & ~3;
    __syncthreads();  // previous tile's readers done before overwrite

    if (rl0 < cnt) {
      const unsigned int r0 = idxg[base + off + rl0];
      const float4 v = xf4[(size_t)r0 * 8 + pt];
      xsT[pt * 4 + 0][rl0] = v.x;
      xsT[pt * 4 + 1][rl0] = v.y;
      xsT[pt * 4 + 2][rl0] = v.z;
      xsT[pt * 4 + 3][rl0] = v.w;
    }
    const int rl1 = rl0 + 32;
    if (rl1 < cnt) {
      const unsigned int r1 = idxg[base + off + rl1];
      const float4 v = xf4[(size_t)r1 * 8 + pt];
      xsT[pt * 4 + 0][rl1] = v.x;
      xsT[pt * 4 + 1][rl1] = v.y;
      xsT[pt * 4 + 2][rl1] = v.z;
      xsT[pt * 4 + 3][rl1] = v.w;
    }
    for (int e = cnt * DD + tid; e < cnt4 * DD; e += 256)
      xsT[e & 31][e >> 5] = 0.f;  // zero-pad rows to multiple of 4
    __syncthreads();

    const int gmax = cnt4 >> 2;
    for (int g = grp; g < gmax; g += 4) {  // row-quads strided by group
      float4 Af[4], Bf[4];
#pragma unroll
      for (int r = 0; r < 4; ++r)
        Af[r] = *(const float4*)&xsT[ti + 8 * r][4 * g];
#pragma unroll
      for (int c2 = 0; c2 < 4; ++c2)
        Bf[c2] = *(const float4*)&xsT[tj + 8 * c2][4 * g];
#pragma unroll
      for (int r = 0; r < 4; ++r)
#pragma unroll
        for (int c2 = 0; c2 < 4; ++c2)
          cc[r][c2] += Af[r].x * Bf[c2].x + Af[r].y * Bf[c2].y +
                       Af[r].z * Bf[c2].z + Af[r].w * Bf[c2].w;
      if (tj == 0) {
#pragma unroll
        for (int r = 0; r < 4; ++r)
          sd[r] += Af[r].x + Af[r].y + Af[r].z + Af[r].w;
      }
    }
  }

  // cross-group reduction through LDS, then triangular flush
#pragma unroll
  for (int r = 0; r < 4; ++r)
    *(float4*)&red[grp][t6][r * 4] =
        make_float4(cc[r][0], cc[r][1], cc[r][2], cc[r][3]);
  if (tj == 0) {
#pragma unroll
    for (int r = 0; r < 4; ++r) sdred[grp][ti + 8 * r] = sd[r];
  }
  __syncthreads();

  float* m2k = m2low_g + k * 528;
  {
    const int t6r = tid >> 2;        // which 4x4 tile (0..63)
    const int rr = tid & 3;          // which row of that tile
    const int tir = t6r >> 3, tjr = t6r & 7;
    const int i = tir + 8 * rr;
    float4 v0 = *(const float4*)&red[0][t6r][rr * 4];
    const float4 v1 = *(const float4*)&red[1][t6r][rr * 4];
    const float4 v2 = *(const float4*)&red[2][t6r][rr * 4];
    const float4 v3 = *(const float4*)&red[3][t6r][rr * 4];
    v0.x += v1.x + v2.x + v3.x;
    v0.y += v1.y + v2.y + v3.y;
    v0.z += v1.z + v2.z + v3.z;
    v0.w += v1.w + v2.w + v3.w;
    const float vv[4] = {v0.x, v0.y, v0.z, v0.w};
#pragma unroll
    for (int q = 0; q < 4; ++q) {
      const int j = tjr + 8 * q;
      if (j <= i) atomicAdd(&m2k[TRI(i, j)], vv[q]);
    }
  }
  if (tid < DD) {
    const float s =
        sdred[0][tid] + sdred[1][tid] + sdred[2][tid] + sdred[3][tid];
    atomicAdd(&sums_g[k * DD + tid], s);
  }
}

// finalize (R15 verbatim, validated): one block per cluster; last-arriving
// block writes the output scalar (fence only at pipeline END).
__global__ __launch_bounds__(256) void finalize_kernel(
    const float* __restrict__ fill_g, const int* __restrict__ hist_g,
    const float* __restrict__ sums_g, const float* __restrict__ m2low_g,
    const float* __restrict__ ft, const float* __restrict__ mt,
    const float* __restrict__ ct, float* __restrict__ lossAcc,
    int* __restrict__ doneF, float* __restrict__ out) {
  __shared__ float meanS[DD];
  __shared__ float wred[4];
  const int t = threadIdx.x;
  const int k = blockIdx.x;

  const float inv = 1.0f / fmaxf((float)hist_g[k], 1.0f);
  if (t < DD) meanS[t] = sums_g[k * DD + t] * inv;
  __syncthreads();

  float acc = 0.f;
  if (t < DD) {
    const float d = meanS[t] - mt[k * DD + t];
    acc += d * d * (1.0f / (KK * DD));
  }
  if (t == 0) {
    const float f = fill_g[k] * (1.0f / (float)NR) - ft[k];
    acc += f * f * (1.0f / KK);
  }
  const float* m2k = m2low_g + k * 528;
  const float* ctk = ct + k * (DD * DD);
#pragma unroll
  for (int u = 0; u < 4; ++u) {
    const int e = t + 256 * u;
    const int i = e >> 5, j = e & 31;
    const int idx = (i >= j) ? TRI(i, j) : TRI(j, i);
    const float cov = m2k[idx] * inv - meanS[i] * meanS[j];
    const float d = cov - ctk[e];
    acc += d * d * (1.0f / (KK * DD * DD));
  }

  acc += __shfl_xor(acc, 32, 64);
  acc += __shfl_xor(acc, 16, 64);
  acc += __shfl_xor(acc, 8, 64);
  acc += __shfl_xor(acc, 4, 64);
  acc += __shfl_xor(acc, 2, 64);
  acc += __shfl_xor(acc, 1, 64);
  if ((t & 63) == 0) wred[t >> 6] = acc;
  __syncthreads();
  if (t == 0) {
    atomicAdd(lossAcc, wred[0] + wred[1] + wred[2] + wred[3]);
    __threadfence();  // release: lossAcc visible before doneF bump
    if (atomicAdd(doneF, 1) == KK - 1) {
      out[0] = atomicAdd(lossAcc, 0.0f);  // coherent-path read
    }
  }
}

extern "C" void kernel_launch(void* const* d_in, const int* in_sizes, int n_in,
                              void* d_out, int out_size, void* d_ws,
                              size_t ws_size, hipStream_t stream) {
  (void)in_sizes; (void)n_in; (void)out_size; (void)ws_size;
  const float* x = (const float*)d_in[0];
  const float* centers = (const float*)d_in[1];
  const float* ft = (const float*)d_in[2];
  const float* mt = (const float*)d_in[3];
  const float* ct = (const float*)d_in[4];
  float* out = (float*)d_out;

  float* ws = (float*)d_ws;
  float* fill_g = ws;                                   // 64
  float* lossAcc = ws + 64;                             // 1
  int* doneF = (int*)(ws + 67);                         // 1
  int* hist_g = (int*)(ws + 128);                       // 64
  int* cursor = (int*)(ws + 320);                       // 64
  float* m2low_g = ws + 1824;                           // 33792
  float* sums_g = ws + 35616;                           // 2048
  unsigned char* pred8 = (unsigned char*)(ws + 37664);  // N bytes
  unsigned int* idxg = (unsigned int*)(ws + 70432);     // N uints (512 KB)

  // zero fill_g/lossAcc/doneF/hist/cursor only (1.5 KB); m2low/sums are
  // zeroed inside scatter (stream-ordered ahead of syrk's atomics).
  hipMemsetAsync(d_ws, 0, (size_t)384 * sizeof(float), stream);

  phase1_kernel<<<NR / 256, 256, 0, stream>>>(x, centers, fill_g, hist_g,
                                              pred8);
  scatter_kernel<<<NR / 256, 256, 0, stream>>>(pred8, hist_g, cursor, idxg,
                                               (float4*)m2low_g);
  syrk_kernel<<<GRIDW, 256, 0, stream>>>(x, idxg, hist_g, m2low_g, sums_g);
  finalize_kernel<<<KK, 256, 0, stream>>>(fill_g, hist_g, sums_g, m2low_g, ft,
                                          mt, ct, lossAcc, doneF, out);
}